// Round 18
// baseline (99.490 us; speedup 1.0000x reference)
//
#include <hip/hip_runtime.h>
#include <hip/hip_bf16.h>
#include <stdint.h>

typedef float f32x4 __attribute__((ext_vector_type(4)));
typedef float f32x16 __attribute__((ext_vector_type(16)));
typedef __bf16 bf16x8 __attribute__((ext_vector_type(8)));
typedef unsigned int uint2v __attribute__((ext_vector_type(2)));

#define D_MODEL 1024
#define NHEAD 16
#define DHEAD 64
#define BATCH 2
#define SEQ 2048
#define MROWS (BATCH*SEQ)   // 4096
#define N3 (3*D_MODEL)      // 3072

// 0.125 (1/sqrt(Dh)) * log2(e): folded into Q so attention uses exp2 directly
#define SCALE_LOG2E 0.1803368801111244f

__device__ __forceinline__ unsigned short f2bf(float f) {
  unsigned int u = __float_as_uint(f);
  u += 0x7FFF + ((u >> 16) & 1);
  return (unsigned short)(u >> 16);
}

// pack two f32 -> one dword of 2 bf16 (elem0 = x in low 16)
#define CVTPK(d, x, y) asm("v_cvt_pk_bf16_f32 %0, %1, %2" : "=v"(d) : "v"(x), "v"(y))
// swap lanes 32-63 of x with lanes 0-31 of y
#define SWAP32(x, y) do { uint2v _r = __builtin_amdgcn_permlane32_swap((x), (y), false, false); \
                          (x) = _r[0]; (y) = _r[1]; } while (0)

// async global->LDS, 16B per lane. lds ptr must be wave-uniform base.
__device__ __forceinline__ void gload_lds16(const void* g, void* l) {
  __builtin_amdgcn_global_load_lds(
      (const __attribute__((address_space(1))) unsigned int*)g,
      (__attribute__((address_space(3))) unsigned int*)l, 16, 0, 0);
}

// ------ fused prep: x fp32->bf16 convert + both weight transpose-converts ------
__global__ __launch_bounds__(256) void prep(const float* __restrict__ x,
                                            unsigned short* __restrict__ xb,
                                            const float* __restrict__ qkvw,
                                            unsigned short* __restrict__ oq,
                                            const float* __restrict__ projw,
                                            unsigned short* __restrict__ op) {
  int bid = blockIdx.x;
  if (bid < 2048) {
    int n4 = MROWS*D_MODEL/4;
    int i = bid*256 + threadIdx.x;
    int stride = 2048*256;
    for (; i < n4; i += stride) {
      float4 f = ((const float4*)x)[i];
      ushort4 u;
      u.x = f2bf(f.x); u.y = f2bf(f.y); u.z = f2bf(f.z); u.w = f2bf(f.w);
      ((ushort4*)xb)[i] = u;
    }
    return;
  }
  __shared__ float tile[32][33];
  int id = bid - 2048;
  const float* in; unsigned short* out; int K, N, n0, k0;
  if (id < 3072) { in = qkvw;  out = oq; K = 1024; N = 3072; n0 = (id % 96)*32; k0 = (id / 96)*32; }
  else { id -= 3072; in = projw; out = op; K = 1024; N = 1024; n0 = (id % 32)*32; k0 = (id / 32)*32; }
  int tx = threadIdx.x & 31, ty = threadIdx.x >> 5;  // ty 0..7
#pragma unroll
  for (int i = 0; i < 4; ++i)
    tile[ty + 8*i][tx] = in[(size_t)(k0 + ty + 8*i)*N + n0 + tx];
  __syncthreads();
#pragma unroll
  for (int i = 0; i < 4; ++i)
    out[(size_t)(n0 + ty + 8*i)*K + k0 + tx] = f2bf(tile[tx][ty + 8*i]);
}

// ---------------- bf16 QKV GEMM: 64x128 tile -> grid 1536 = 6 blocks/CU -------
// Latency-hiding via block count: qkv at 128^2 was grid-limited to 3 blocks/CU
// with ~75% stall per iter; 64x128 (gemm_proj's proven structure, identical
// per-FLOP rate) doubles co-resident blocks. LDS 24KB staging + 16KB c-tile.
#define BM 64
#define BN 128
#define BK 64

__global__ __launch_bounds__(256, 4) void gemm_bt(
    const unsigned short* __restrict__ A,
    const unsigned short* __restrict__ Bt,
    const float* __restrict__ bias,
    int K, int N,
    unsigned short* __restrict__ qo,
    unsigned short* __restrict__ ko,
    unsigned short* __restrict__ vo)
{
  __shared__ unsigned short lds_all[BM*BK + BN*BK];   // 24 KB
  unsigned short* a_lds = lds_all;
  unsigned short* b_lds = lds_all + BM*BK;
  int tid = threadIdx.x;
  int lane = tid & 63, wid = tid >> 6;
  int wr = wid >> 1, wc = wid & 1;
  int lr = lane & 15, lh = lane >> 4;

  // XCD-chunked (n,m) from linear block id (requires gridDim.x % 8 == 0)
  int bid = blockIdx.y*gridDim.x + blockIdx.x;
  int cN = gridDim.x >> 3;                 // 3
  int xcd = bid & 7;
  int j = (bid >> 3) % cN;
  int m = bid / (cN << 3);
  int M0 = m*BM, N0 = (xcd*cN + j)*BN;

  // staging: thread covers 16B at row (32i + tid>>3); SOURCE col-slot
  // pre-swizzled by row&7 (row&7 == (tid>>3)&7, 32 | 8) -> linear LDS dest.
  int srow = tid >> 3;        // 0..31
  int scol = (((tid & 7) ^ ((tid >> 3) & 7)))*8;
  const unsigned short* aP = A  + (size_t)(M0 + srow)*K + scol;
  const unsigned short* bP = Bt + (size_t)(N0 + srow)*K + scol;
  char* aL = (char*)a_lds + wid*1024;   // wave-uniform dest base
  char* bL = (char*)b_lds + wid*1024;

  int KT = K/BK;

  f32x4 acc[2][4];
#pragma unroll
  for (int i = 0; i < 2; ++i)
#pragma unroll
    for (int j2 = 0; j2 < 4; ++j2) acc[i][j2] = (f32x4){0.f, 0.f, 0.f, 0.f};

  for (int kt = 0; kt < KT; ++kt) {
    const unsigned short* ap = aP + kt*BK;
    const unsigned short* bp = bP + kt*BK;
#pragma unroll
    for (int i = 0; i < 2; ++i)
      gload_lds16(ap + (size_t)32*i*K, aL + i*4096);
#pragma unroll
    for (int i = 0; i < 4; ++i)
      gload_lds16(bp + (size_t)32*i*K, bL + i*4096);
    __syncthreads();
#pragma unroll
    for (int ks = 0; ks < 2; ++ks) {
      bf16x8 af[2], bf[4];
#pragma unroll
      for (int mi = 0; mi < 2; ++mi)
        af[mi] = *(const bf16x8*)&a_lds[(wr*32 + mi*16 + lr)*BK + (((ks*4 + lh) ^ (lr & 7))*8)];
#pragma unroll
      for (int ni = 0; ni < 4; ++ni)
        bf[ni] = *(const bf16x8*)&b_lds[(wc*64 + ni*16 + lr)*BK + (((ks*4 + lh) ^ (lr & 7))*8)];
#pragma unroll
      for (int mi = 0; mi < 2; ++mi)
#pragma unroll
        for (int ni = 0; ni < 4; ++ni)
          acc[mi][ni] = __builtin_amdgcn_mfma_f32_16x16x32_bf16(af[mi], bf[ni], acc[mi][ni], 0, 0, 0);
    }
    __syncthreads();
  }

  // epilogue via LDS: c-tile reuses lds_all (16KB needed, 24KB available).
  // region 0=q (scaled), 1=k: c[64 m][128 n]; region 2=v: c[128 n][64 m].
  // 16B-granule XOR swizzle keyed by row&7 on both sides.
  int region = N0 >> 10;
  unsigned short* c = lds_all;
#pragma unroll
  for (int mi = 0; mi < 2; ++mi) {
#pragma unroll
    for (int ni = 0; ni < 4; ++ni) {
      int n = wc*64 + ni*16 + lr;
      float bs = bias[N0 + n];
#pragma unroll
      for (int r = 0; r < 4; ++r) {
        int mm = wr*32 + mi*16 + lh*4 + r;
        float v = acc[mi][ni][r] + bs;
        if (region == 0) v *= SCALE_LOG2E;
        unsigned short u = f2bf(v);
        if (region < 2)
          c[mm*128 + ((((n >> 3) ^ (mm & 7)) << 3) | (n & 7))] = u;
        else
          c[n*64 + ((((mm >> 3) ^ (n & 7)) << 3) | (mm & 7))] = u;
      }
    }
  }
  __syncthreads();

  // stream out: 4 iters x 256 threads, each 16B; 8 lanes cover one 128B line.
#pragma unroll
  for (int it = 0; it < 4; ++it) {
    int idx = it*256 + tid;          // 0..1023
    int s = idx & 7;
    int chunk = idx >> 3;            // 0..127
    if (region < 2) {
      int row = chunk >> 1, half = chunk & 1;           // row 0..63
      int4 v4 = *(const int4*)&c[row*128 + (((half*8 + s) ^ (row & 7)) << 3)];
      int tg = M0 + row;
      int b = tg >> 11, tt = tg & (SEQ-1);
      int h = ((N0 & 1023) + half*64) >> 6;
      unsigned short* dst = (region == 0) ? qo : ko;
      *(int4*)(dst + (((size_t)(b*NHEAD + h))*SEQ + tt)*DHEAD + s*8) = v4;
    } else {
      int n = chunk;                                     // 0..127
      int4 v4 = *(const int4*)&c[n*64 + ((s ^ (n & 7)) << 3)];
      int cgl = (N0 - 2*D_MODEL) + n;
      int h = cgl >> 6, d = cgl & 63;
      int tg = M0 + s*8;
      int b = tg >> 11, tt = tg & (SEQ-1);
      *(int4*)(vo + (((size_t)(b*NHEAD + h))*DHEAD + d)*SEQ + tt) = v4;
    }
  }
}

// ---------------- proj GEMM: 64x128 tile -> grid 512 = 2 blocks/CU ------------
#define PM 64
#define PN 128

__global__ __launch_bounds__(256, 2) void gemm_proj(
    const unsigned short* __restrict__ A,
    const unsigned short* __restrict__ Bt,
    const float* __restrict__ bias,
    float* __restrict__ fo)
{
  __shared__ unsigned short a_lds[PM*BK];   // 8 KB
  __shared__ unsigned short b_lds[PN*BK];   // 16 KB
  int tid = threadIdx.x;
  int lane = tid & 63, wid = tid >> 6;
  int wr = wid >> 1, wc = wid & 1;
  int lr = lane & 15, lh = lane >> 4;

  int M0 = blockIdx.y*PM, N0 = blockIdx.x*PN;
  const int K = D_MODEL, N = D_MODEL;

  int srow = tid >> 3;
  int scol = (((tid & 7) ^ ((tid >> 3) & 7)))*8;
  const unsigned short* aP = A  + (size_t)(M0 + srow)*K + scol;
  const unsigned short* bP = Bt + (size_t)(N0 + srow)*K + scol;
  char* aL = (char*)a_lds + wid*1024;
  char* bL = (char*)b_lds + wid*1024;

  f32x4 acc[2][4];
#pragma unroll
  for (int i = 0; i < 2; ++i)
#pragma unroll
    for (int j2 = 0; j2 < 4; ++j2) acc[i][j2] = (f32x4){0.f, 0.f, 0.f, 0.f};

  for (int kt = 0; kt < K/BK; ++kt) {
    const unsigned short* ap = aP + kt*BK;
    const unsigned short* bp = bP + kt*BK;
#pragma unroll
    for (int i = 0; i < 2; ++i)
      gload_lds16(ap + (size_t)32*i*K, aL + i*4096);
#pragma unroll
    for (int i = 0; i < 4; ++i)
      gload_lds16(bp + (size_t)32*i*K, bL + i*4096);
    __syncthreads();
#pragma unroll
    for (int ks = 0; ks < 2; ++ks) {
      bf16x8 af[2], bf[4];
#pragma unroll
      for (int mi = 0; mi < 2; ++mi)
        af[mi] = *(const bf16x8*)&a_lds[(wr*32 + mi*16 + lr)*BK + (((ks*4 + lh) ^ (lr & 7))*8)];
#pragma unroll
      for (int ni = 0; ni < 4; ++ni)
        bf[ni] = *(const bf16x8*)&b_lds[(wc*64 + ni*16 + lr)*BK + (((ks*4 + lh) ^ (lr & 7))*8)];
#pragma unroll
      for (int mi = 0; mi < 2; ++mi)
#pragma unroll
        for (int ni = 0; ni < 4; ++ni)
          acc[mi][ni] = __builtin_amdgcn_mfma_f32_16x16x32_bf16(af[mi], bf[ni], acc[mi][ni], 0, 0, 0);
    }
    __syncthreads();
  }

#pragma unroll
  for (int mi = 0; mi < 2; ++mi) {
#pragma unroll
    for (int ni = 0; ni < 4; ++ni) {
      int ncol = N0 + wc*64 + ni*16 + lr;
      float bs = bias[ncol];
      int mbase = M0 + wr*32 + mi*16 + lh*4;
#pragma unroll
      for (int r = 0; r < 4; ++r)
        fo[(size_t)(mbase + r)*N + ncol] = acc[mi][ni][r] + bs;
    }
  }
}

// ---------------- causal flash attention (cooperative LDS-staged K/V) ----------
// Block = 4 waves on a 128-q tile, KV tile = 128 per barrier round.
// Complementary-pair LPT mapping balances per-CU tile-rounds.
#define NQT128 (SEQ/128)   // 16

__global__ __launch_bounds__(256, 2) void attn_fwd(
    const unsigned short* __restrict__ q,
    const unsigned short* __restrict__ kk,
    const unsigned short* __restrict__ vt,
    unsigned short* __restrict__ out)
{
  __shared__ __align__(16) char smem[2][32768];

  int tid = threadIdx.x, lane = tid & 63, wid = tid >> 6;
  int idx = blockIdx.x;
  int slot = idx & 255;
  int qt = (idx < 256) ? (NQT128 - 1 - (slot >> 5)) : (slot >> 5);
  int bh = idx & 31;                     // b*NHEAD + h
  int b = bh >> 4, h = bh & 15;
  int q0w = qt*128 + wid*32;             // this wave's q rows
  int l31 = lane & 31, hl = lane >> 5;

  const unsigned short* qb = q  + ((size_t)bh*SEQ)*DHEAD;
  const unsigned short* kb = kk + ((size_t)bh*SEQ)*DHEAD;
  const unsigned short* vb = vt + ((size_t)bh*DHEAD)*SEQ;

  int srow = lane >> 3;
  int sslot = (lane & 7) ^ srow;

  // fragment-read byte offsets within one 8KB 64-row sub-tile
  int roff[2][4];
#pragma unroll
  for (int j = 0; j < 2; ++j)
#pragma unroll
    for (int st = 0; st < 4; ++st)
      roff[j][st] = (j*32 + l31)*128 + (((2*st + hl) ^ (l31 & 7))*16);

  bf16x8 qf[4];
#pragma unroll
  for (int st = 0; st < 4; ++st)
    qf[st] = *(const bf16x8*)(qb + (size_t)(q0w + l31)*DHEAD + st*16 + hl*8);

  f32x16 o0a, o0b, o1a, o1b;   // split PV accumulators (chain depth /2)
#pragma unroll
  for (int i = 0; i < 16; ++i) { o0a[i] = 0.f; o0b[i] = 0.f; o1a[i] = 0.f; o1b[i] = 0.f; }
  float l = 0.f;
  int qg = q0w + l31;

  int nkv = qt + 1;   // 128-wide kv tiles covering q < (qt+1)*128

  // K: smem[buf][0..16KB)  rows 0..127 x 128B, XOR-swizzled 16B slots
  // V: smem[buf][16KB + jj*8KB ...) two 64x128B halves, same swizzle
#define STAGE(bufi, kvbase) do {                                                   \
    char* kd = smem[bufi] + wid*4096;                                              \
    _Pragma("unroll")                                                              \
    for (int i = 0; i < 4; ++i)                                                    \
      gload_lds16(kb + (size_t)((kvbase) + wid*32 + i*8 + srow)*DHEAD + sslot*8,   \
                  kd + i*1024);                                                    \
    _Pragma("unroll")                                                              \
    for (int jj = 0; jj < 2; ++jj) {                                               \
      char* vd = smem[bufi] + 16384 + jj*8192 + wid*2048;                          \
      _Pragma("unroll")                                                            \
      for (int i = 0; i < 2; ++i)                                                  \
        gload_lds16(vb + (size_t)(wid*16 + i*8 + srow)*SEQ + (kvbase) + jj*64 +    \
                    sslot*8, vd + i*1024);                                         \
    }                                                                              \
  } while (0)

  STAGE(0, 0);
  __syncthreads();

  for (int t = 0; t < nkv; ++t) {
    int cur = t & 1;
    if (t + 1 < nkv) STAGE(cur ^ 1, (t+1)*128);

#pragma unroll
    for (int jj = 0; jj < 2; ++jj) {
      int kv0 = t*128 + jj*64;
      if (kv0 <= q0w + 31) {   // wave-uniform skip of fully-masked halves
        const char* kbase = (const char*)smem[cur] + jj*8192;
        const char* vbase = (const char*)smem[cur] + 16384 + jj*8192;

        f32x16 s0, s1;
#pragma unroll
        for (int i = 0; i < 16; ++i) { s0[i] = 0.f; s1[i] = 0.f; }

        __builtin_amdgcn_s_setprio(1);
#pragma unroll
        for (int st = 0; st < 4; ++st) {
          bf16x8 k0 = *(const bf16x8*)(kbase + roff[0][st]);
          bf16x8 k1 = *(const bf16x8*)(kbase + roff[1][st]);
          s0 = __builtin_amdgcn_mfma_f32_32x32x16_bf16(k0, qf[st], s0, 0, 0, 0);
          s1 = __builtin_amdgcn_mfma_f32_32x32x16_bf16(k1, qf[st], s1, 0, 0, 0);
        }
        __builtin_amdgcn_s_setprio(0);

        if (kv0 + 63 > qg - 31) {
#pragma unroll
          for (int r = 0; r < 16; ++r) {
            int kl = (r&3) + 8*(r>>2) + 4*hl;
            if (kv0 + kl      > qg) s0[r] = -1e30f;
            if (kv0 + 32 + kl > qg) s1[r] = -1e30f;
          }
        }

#pragma unroll
        for (int j = 0; j < 2; ++j) {
          const f32x16& sj = j ? s1 : s0;
          float p[16];
#pragma unroll
          for (int r = 0; r < 16; ++r) p[r] = __builtin_amdgcn_exp2f(sj[r]);
          float t0 = (p[0]+p[1]) + (p[2]+p[3]);
          float t1 = (p[4]+p[5]) + (p[6]+p[7]);
          float t2 = (p[8]+p[9]) + (p[10]+p[11]);
          float t3 = (p[12]+p[13]) + (p[14]+p[15]);
          l += (t0+t1) + (t2+t3);
          uint32_t a0,a1,a2,a3,b0,b1,b2,b3;
          CVTPK(a0, p[0],  p[1]);  CVTPK(a1, p[2],  p[3]);
          CVTPK(b0, p[4],  p[5]);  CVTPK(b1, p[6],  p[7]);
          CVTPK(a2, p[8],  p[9]);  CVTPK(a3, p[10], p[11]);
          CVTPK(b2, p[12], p[13]); CVTPK(b3, p[14], p[15]);
          SWAP32(a0, b0); SWAP32(a1, b1); SWAP32(a2, b2); SWAP32(a3, b3);
          union { uint32_t u[4]; bf16x8 v; } pf0, pf1;
          pf0.u[0]=a0; pf0.u[1]=a1; pf0.u[2]=b0; pf0.u[3]=b1;   // k-slot 2j
          pf1.u[0]=a2; pf1.u[1]=a3; pf1.u[2]=b2; pf1.u[3]=b3;   // k-slot 2j+1
          bf16x8 v00 = *(const bf16x8*)(vbase + roff[0][2*j]);
          bf16x8 v01 = *(const bf16x8*)(vbase + roff[1][2*j]);
          bf16x8 v10 = *(const bf16x8*)(vbase + roff[0][2*j + 1]);
          bf16x8 v11 = *(const bf16x8*)(vbase + roff[1][2*j + 1]);
          __builtin_amdgcn_s_setprio(1);
          o0a = __builtin_amdgcn_mfma_f32_32x32x16_bf16(v00, pf0.v, o0a, 0, 0, 0);
          o1a = __builtin_amdgcn_mfma_f32_32x32x16_bf16(v01, pf0.v, o1a, 0, 0, 0);
          o0b = __builtin_amdgcn_mfma_f32_32x32x16_bf16(v10, pf1.v, o0b, 0, 0, 0);
          o1b = __builtin_amdgcn_mfma_f32_32x32x16_bf16(v11, pf1.v, o1b, 0, 0, 0);
          __builtin_amdgcn_s_setprio(0);
        }
      }
    }
    __syncthreads();
  }
#undef STAGE

  // epilogue: combine split accumulators + half-wave sums, normalize, pack.
  f32x16 o0 = o0a + o0b;
  f32x16 o1 = o1a + o1b;
  l += __shfl_xor(l, 32);
  float inv = 1.f / l;
  o0 *= inv; o1 *= inv;

  // obuf[128 q][64 d] bf16 (16KB), 8B-granule XOR swizzle.
  unsigned short* obuf = (unsigned short*)smem;
  int qrow = wid*32 + l31;
  int xk = (qrow & 7) << 1;
#pragma unroll
  for (int g = 0; g < 4; ++g) {
    uint32_t w0, w1;
    CVTPK(w0, o0[4*g],   o0[4*g+1]);
    CVTPK(w1, o0[4*g+2], o0[4*g+3]);
    uint2 pk0 = {w0, w1};
    *(uint2*)&obuf[qrow*64 + (((2*g + hl) ^ xk) << 2)] = pk0;
    CVTPK(w0, o1[4*g],   o1[4*g+1]);
    CVTPK(w1, o1[4*g+2], o1[4*g+3]);
    uint2 pk1 = {w0, w1};
    *(uint2*)&obuf[qrow*64 + (((8 + 2*g + hl) ^ xk) << 2)] = pk1;
  }
  __syncthreads();

#pragma unroll
  for (int it = 0; it < 4; ++it) {
    int idx2 = it*256 + tid;          // 0..1023
    int s = idx2 & 7, row = idx2 >> 3;
    int4 v4 = *(const int4*)&obuf[row*64 + ((s ^ (row & 7)) << 3)];
    int tq = qt*128 + row;
    *(int4*)(out + ((size_t)(b*SEQ) + tq)*D_MODEL + h*DHEAD + s*8) = v4;
  }
}

// ---------------- launcher ----------------
extern "C" void kernel_launch(void* const* d_in, const int* in_sizes, int n_in,
                              void* d_out, int out_size, void* d_ws, size_t ws_size,
                              hipStream_t stream) {
  const float* x      = (const float*)d_in[0];
  const float* qkv_w  = (const float*)d_in[2];
  const float* qkv_b  = (const float*)d_in[3];
  const float* proj_w = (const float*)d_in[4];
  const float* proj_b = (const float*)d_in[5];

  const size_t MB = 1024*1024;
  if (ws_size < 48*MB) return;
  char* w = (char*)d_ws;
  unsigned short* xb      = (unsigned short*)(w);
  unsigned short* wqkv_t  = (unsigned short*)(w + 8*MB);
  unsigned short* wproj_t = (unsigned short*)(w + 14*MB);
  unsigned short* qbuf    = (unsigned short*)(w + 16*MB);
  unsigned short* kbuf    = (unsigned short*)(w + 24*MB);
  unsigned short* vtbuf   = (unsigned short*)(w + 32*MB);
  unsigned short* aout    = (unsigned short*)(w + 40*MB);

  prep<<<6144, 256, 0, stream>>>(x, xb, qkv_w, wqkv_t, proj_w, wproj_t);
  gemm_bt<<<dim3(N3/BN, MROWS/BM), 256, 0, stream>>>(xb, wqkv_t, qkv_b, D_MODEL, N3,
                                                     qbuf, kbuf, vtbuf);
  attn_fwd<<<dim3(32*NQT128), 256, 0, stream>>>(qbuf, kbuf, vtbuf, aout);
  gemm_proj<<<dim3(D_MODEL/PN, MROWS/PM), 256, 0, stream>>>(aout, wproj_t, proj_b, (float*)d_out);
}

// Round 19
// 96.003 us; speedup vs baseline: 1.0363x; 1.0363x over previous
//
#include <hip/hip_runtime.h>
#include <hip/hip_bf16.h>
#include <stdint.h>

typedef float f32x4 __attribute__((ext_vector_type(4)));
typedef float f32x16 __attribute__((ext_vector_type(16)));
typedef __bf16 bf16x8 __attribute__((ext_vector_type(8)));
typedef unsigned int uint2v __attribute__((ext_vector_type(2)));

#define D_MODEL 1024
#define NHEAD 16
#define DHEAD 64
#define BATCH 2
#define SEQ 2048
#define MROWS (BATCH*SEQ)   // 4096
#define N3 (3*D_MODEL)      // 3072

// 0.125 (1/sqrt(Dh)) * log2(e): folded into Q so attention uses exp2 directly
#define SCALE_LOG2E 0.1803368801111244f

__device__ __forceinline__ unsigned short f2bf(float f) {
  unsigned int u = __float_as_uint(f);
  u += 0x7FFF + ((u >> 16) & 1);
  return (unsigned short)(u >> 16);
}

// pack two f32 -> one dword of 2 bf16 (elem0 = x in low 16)
#define CVTPK(d, x, y) asm("v_cvt_pk_bf16_f32 %0, %1, %2" : "=v"(d) : "v"(x), "v"(y))
// swap lanes 32-63 of x with lanes 0-31 of y
#define SWAP32(x, y) do { uint2v _r = __builtin_amdgcn_permlane32_swap((x), (y), false, false); \
                          (x) = _r[0]; (y) = _r[1]; } while (0)

// async global->LDS, 16B per lane. lds ptr must be wave-uniform base.
__device__ __forceinline__ void gload_lds16(const void* g, void* l) {
  __builtin_amdgcn_global_load_lds(
      (const __attribute__((address_space(1))) unsigned int*)g,
      (__attribute__((address_space(3))) unsigned int*)l, 16, 0, 0);
}

// ------ fused prep: x fp32->bf16 convert + both weight transpose-converts ------
__global__ __launch_bounds__(256) void prep(const float* __restrict__ x,
                                            unsigned short* __restrict__ xb,
                                            const float* __restrict__ qkvw,
                                            unsigned short* __restrict__ oq,
                                            const float* __restrict__ projw,
                                            unsigned short* __restrict__ op) {
  int bid = blockIdx.x;
  if (bid < 2048) {
    int n4 = MROWS*D_MODEL/4;
    int i = bid*256 + threadIdx.x;
    int stride = 2048*256;
    for (; i < n4; i += stride) {
      float4 f = ((const float4*)x)[i];
      ushort4 u;
      u.x = f2bf(f.x); u.y = f2bf(f.y); u.z = f2bf(f.z); u.w = f2bf(f.w);
      ((ushort4*)xb)[i] = u;
    }
    return;
  }
  __shared__ float tile[32][33];
  int id = bid - 2048;
  const float* in; unsigned short* out; int K, N, n0, k0;
  if (id < 3072) { in = qkvw;  out = oq; K = 1024; N = 3072; n0 = (id % 96)*32; k0 = (id / 96)*32; }
  else { id -= 3072; in = projw; out = op; K = 1024; N = 1024; n0 = (id % 32)*32; k0 = (id / 32)*32; }
  int tx = threadIdx.x & 31, ty = threadIdx.x >> 5;  // ty 0..7
#pragma unroll
  for (int i = 0; i < 4; ++i)
    tile[ty + 8*i][tx] = in[(size_t)(k0 + ty + 8*i)*N + n0 + tx];
  __syncthreads();
#pragma unroll
  for (int i = 0; i < 4; ++i)
    out[(size_t)(n0 + ty + 8*i)*K + k0 + tx] = f2bf(tile[tx][ty + 8*i]);
}

// ---------------- bf16 QKV GEMM: 128x128 tile (m97 structure + T2 swizzle) ----
// 4 waves / 256 threads / 3 blocks-per-CU: both fewer waves (R16) and more
// blocks via 64x128 tiles (R18) regressed — this is the structure floor.
#define BM 128
#define BN 128
#define BK 64

__global__ __launch_bounds__(256, 3) void gemm_bt(
    const unsigned short* __restrict__ A,
    const unsigned short* __restrict__ Bt,
    const float* __restrict__ bias,
    int K, int N,
    unsigned short* __restrict__ qo,
    unsigned short* __restrict__ ko,
    unsigned short* __restrict__ vo)
{
  __shared__ unsigned short lds_all[BM*BK + BN*BK];   // 32 KB
  unsigned short* a_lds = lds_all;
  unsigned short* b_lds = lds_all + BM*BK;
  int tid = threadIdx.x;
  int lane = tid & 63, wid = tid >> 6;
  int wr = wid >> 1, wc = wid & 1;
  int lr = lane & 15, lh = lane >> 4;

  // XCD-chunked (n,m) from linear block id (requires gridDim.x % 8 == 0)
  int bid = blockIdx.y*gridDim.x + blockIdx.x;
  int cN = gridDim.x >> 3;
  int xcd = bid & 7;
  int j = (bid >> 3) % cN;
  int m = bid / (cN << 3);
  int M0 = m*BM, N0 = (xcd*cN + j)*BN;

  // staging: thread covers 16B at row tid>>3; SOURCE col-slot pre-swizzled by
  // row&7 so that LDS (linear dest) ends up XOR-swizzled.
  int srow = tid >> 3;        // 0..31 (+32*i)
  int scol = (((tid & 7) ^ ((tid >> 3) & 7)))*8;
  const unsigned short* aP = A  + (size_t)(M0 + srow)*K + scol;
  const unsigned short* bP = Bt + (size_t)(N0 + srow)*K + scol;
  char* aL = (char*)a_lds + wid*1024;   // wave-uniform dest base
  char* bL = (char*)b_lds + wid*1024;

  int KT = K/BK;

  f32x4 acc[4][4];
#pragma unroll
  for (int i = 0; i < 4; ++i)
#pragma unroll
    for (int j2 = 0; j2 < 4; ++j2) acc[i][j2] = (f32x4){0.f, 0.f, 0.f, 0.f};

  for (int kt = 0; kt < KT; ++kt) {
    const unsigned short* ap = aP + kt*BK;
    const unsigned short* bp = bP + kt*BK;
#pragma unroll
    for (int i = 0; i < 4; ++i) {
      gload_lds16(ap + (size_t)32*i*K, aL + i*4096);
      gload_lds16(bp + (size_t)32*i*K, bL + i*4096);
    }
    __syncthreads();
#pragma unroll
    for (int ks = 0; ks < 2; ++ks) {
      bf16x8 af[4], bf[4];
#pragma unroll
      for (int mi = 0; mi < 4; ++mi)
        af[mi] = *(const bf16x8*)&a_lds[(wr*64 + mi*16 + lr)*BK + (((ks*4 + lh) ^ (lr & 7))*8)];
#pragma unroll
      for (int ni = 0; ni < 4; ++ni)
        bf[ni] = *(const bf16x8*)&b_lds[(wc*64 + ni*16 + lr)*BK + (((ks*4 + lh) ^ (lr & 7))*8)];
#pragma unroll
      for (int mi = 0; mi < 4; ++mi)
#pragma unroll
        for (int ni = 0; ni < 4; ++ni)
          acc[mi][ni] = __builtin_amdgcn_mfma_f32_16x16x32_bf16(af[mi], bf[ni], acc[mi][ni], 0, 0, 0);
    }
    __syncthreads();
  }

  // epilogue via LDS: c-tile 128x128 bf16 (32KB) reuses lds_all.
  int region = N0 >> 10;
  unsigned short* c = lds_all;
#pragma unroll
  for (int mi = 0; mi < 4; ++mi) {
#pragma unroll
    for (int ni = 0; ni < 4; ++ni) {
      int n = wc*64 + ni*16 + lr;
      float bs = bias[N0 + n];
#pragma unroll
      for (int r = 0; r < 4; ++r) {
        int mm = wr*64 + mi*16 + lh*4 + r;
        float v = acc[mi][ni][r] + bs;
        if (region == 0) v *= SCALE_LOG2E;
        unsigned short u = f2bf(v);
        if (region < 2)
          c[mm*128 + ((((n >> 3) ^ (mm & 7)) << 3) | (n & 7))] = u;
        else
          c[n*128 + ((((mm >> 3) ^ (n & 7)) << 3) | (mm & 7))] = u;
      }
    }
  }
  __syncthreads();

  // stream out: 8 iters x 256 threads, each 16B; 8 lanes cover one 128B line.
#pragma unroll
  for (int it = 0; it < 8; ++it) {
    int idx = it*256 + tid;          // 0..2047
    int s = idx & 7;
    int chunk = idx >> 3;            // 0..255
    int row = chunk >> 1, half = chunk & 1;
    int4 v4 = *(const int4*)&c[row*128 + (((half*8 + s) ^ (row & 7)) << 3)];
    if (region < 2) {
      int tg = M0 + row;
      int b = tg >> 11, tt = tg & (SEQ-1);
      int h = (((N0 & 1023)) + half*64) >> 6;
      unsigned short* dst = (region == 0) ? qo : ko;
      *(int4*)(dst + (((size_t)(b*NHEAD + h))*SEQ + tt)*DHEAD + s*8) = v4;
    } else {
      int cgl = (N0 - 2*D_MODEL) + row;
      int h = cgl >> 6, d = cgl & 63;
      int tg = M0 + half*64 + s*8;
      int b = tg >> 11, tt = tg & (SEQ-1);
      *(int4*)(vo + (((size_t)(b*NHEAD + h))*DHEAD + d)*SEQ + tt) = v4;
    }
  }
}

// ---------------- proj GEMM: 64x128 tile -> grid 512 = 2 blocks/CU ------------
#define PM 64
#define PN 128

__global__ __launch_bounds__(256, 2) void gemm_proj(
    const unsigned short* __restrict__ A,
    const unsigned short* __restrict__ Bt,
    const float* __restrict__ bias,
    float* __restrict__ fo)
{
  __shared__ unsigned short a_lds[PM*BK];   // 8 KB
  __shared__ unsigned short b_lds[PN*BK];   // 16 KB
  int tid = threadIdx.x;
  int lane = tid & 63, wid = tid >> 6;
  int wr = wid >> 1, wc = wid & 1;
  int lr = lane & 15, lh = lane >> 4;

  int M0 = blockIdx.y*PM, N0 = blockIdx.x*PN;
  const int K = D_MODEL, N = D_MODEL;

  int srow = tid >> 3;
  int scol = (((tid & 7) ^ ((tid >> 3) & 7)))*8;
  const unsigned short* aP = A  + (size_t)(M0 + srow)*K + scol;
  const unsigned short* bP = Bt + (size_t)(N0 + srow)*K + scol;
  char* aL = (char*)a_lds + wid*1024;
  char* bL = (char*)b_lds + wid*1024;

  f32x4 acc[2][4];
#pragma unroll
  for (int i = 0; i < 2; ++i)
#pragma unroll
    for (int j2 = 0; j2 < 4; ++j2) acc[i][j2] = (f32x4){0.f, 0.f, 0.f, 0.f};

  for (int kt = 0; kt < K/BK; ++kt) {
    const unsigned short* ap = aP + kt*BK;
    const unsigned short* bp = bP + kt*BK;
#pragma unroll
    for (int i = 0; i < 2; ++i)
      gload_lds16(ap + (size_t)32*i*K, aL + i*4096);
#pragma unroll
    for (int i = 0; i < 4; ++i)
      gload_lds16(bp + (size_t)32*i*K, bL + i*4096);
    __syncthreads();
#pragma unroll
    for (int ks = 0; ks < 2; ++ks) {
      bf16x8 af[2], bf[4];
#pragma unroll
      for (int mi = 0; mi < 2; ++mi)
        af[mi] = *(const bf16x8*)&a_lds[(wr*32 + mi*16 + lr)*BK + (((ks*4 + lh) ^ (lr & 7))*8)];
#pragma unroll
      for (int ni = 0; ni < 4; ++ni)
        bf[ni] = *(const bf16x8*)&b_lds[(wc*64 + ni*16 + lr)*BK + (((ks*4 + lh) ^ (lr & 7))*8)];
#pragma unroll
      for (int mi = 0; mi < 2; ++mi)
#pragma unroll
        for (int ni = 0; ni < 4; ++ni)
          acc[mi][ni] = __builtin_amdgcn_mfma_f32_16x16x32_bf16(af[mi], bf[ni], acc[mi][ni], 0, 0, 0);
    }
    __syncthreads();
  }

#pragma unroll
  for (int mi = 0; mi < 2; ++mi) {
#pragma unroll
    for (int ni = 0; ni < 4; ++ni) {
      int ncol = N0 + wc*64 + ni*16 + lr;
      float bs = bias[ncol];
      int mbase = M0 + wr*32 + mi*16 + lh*4;
#pragma unroll
      for (int r = 0; r < 4; ++r)
        fo[(size_t)(mbase + r)*N + ncol] = acc[mi][ni][r] + bs;
    }
  }
}

// ---------------- causal flash attention (cooperative LDS-staged K/V) ----------
// Block = 4 waves on a 128-q tile, KV tile = 128 per barrier round.
// Complementary-pair LPT mapping balances per-CU tile-rounds.
#define NQT128 (SEQ/128)   // 16

__global__ __launch_bounds__(256, 2) void attn_fwd(
    const unsigned short* __restrict__ q,
    const unsigned short* __restrict__ kk,
    const unsigned short* __restrict__ vt,
    unsigned short* __restrict__ out)
{
  __shared__ __align__(16) char smem[2][32768];

  int tid = threadIdx.x, lane = tid & 63, wid = tid >> 6;
  int idx = blockIdx.x;
  int slot = idx & 255;
  int qt = (idx < 256) ? (NQT128 - 1 - (slot >> 5)) : (slot >> 5);
  int bh = idx & 31;                     // b*NHEAD + h
  int b = bh >> 4, h = bh & 15;
  int q0w = qt*128 + wid*32;             // this wave's q rows
  int l31 = lane & 31, hl = lane >> 5;

  const unsigned short* qb = q  + ((size_t)bh*SEQ)*DHEAD;
  const unsigned short* kb = kk + ((size_t)bh*SEQ)*DHEAD;
  const unsigned short* vb = vt + ((size_t)bh*DHEAD)*SEQ;

  int srow = lane >> 3;
  int sslot = (lane & 7) ^ srow;

  // fragment-read byte offsets within one 8KB 64-row sub-tile
  int roff[2][4];
#pragma unroll
  for (int j = 0; j < 2; ++j)
#pragma unroll
    for (int st = 0; st < 4; ++st)
      roff[j][st] = (j*32 + l31)*128 + (((2*st + hl) ^ (l31 & 7))*16);

  bf16x8 qf[4];
#pragma unroll
  for (int st = 0; st < 4; ++st)
    qf[st] = *(const bf16x8*)(qb + (size_t)(q0w + l31)*DHEAD + st*16 + hl*8);

  f32x16 o0a, o0b, o1a, o1b;   // split PV accumulators (chain depth /2)
#pragma unroll
  for (int i = 0; i < 16; ++i) { o0a[i] = 0.f; o0b[i] = 0.f; o1a[i] = 0.f; o1b[i] = 0.f; }
  float l = 0.f;
  int qg = q0w + l31;

  int nkv = qt + 1;   // 128-wide kv tiles covering q < (qt+1)*128

  // K: smem[buf][0..16KB)  rows 0..127 x 128B, XOR-swizzled 16B slots
  // V: smem[buf][16KB + jj*8KB ...) two 64x128B halves, same swizzle
#define STAGE(bufi, kvbase) do {                                                   \
    char* kd = smem[bufi] + wid*4096;                                              \
    _Pragma("unroll")                                                              \
    for (int i = 0; i < 4; ++i)                                                    \
      gload_lds16(kb + (size_t)((kvbase) + wid*32 + i*8 + srow)*DHEAD + sslot*8,   \
                  kd + i*1024);                                                    \
    _Pragma("unroll")                                                              \
    for (int jj = 0; jj < 2; ++jj) {                                               \
      char* vd = smem[bufi] + 16384 + jj*8192 + wid*2048;                          \
      _Pragma("unroll")                                                            \
      for (int i = 0; i < 2; ++i)                                                  \
        gload_lds16(vb + (size_t)(wid*16 + i*8 + srow)*SEQ + (kvbase) + jj*64 +    \
                    sslot*8, vd + i*1024);                                         \
    }                                                                              \
  } while (0)

  STAGE(0, 0);
  __syncthreads();

  for (int t = 0; t < nkv; ++t) {
    int cur = t & 1;
    if (t + 1 < nkv) STAGE(cur ^ 1, (t+1)*128);

#pragma unroll
    for (int jj = 0; jj < 2; ++jj) {
      int kv0 = t*128 + jj*64;
      if (kv0 <= q0w + 31) {   // wave-uniform skip of fully-masked halves
        const char* kbase = (const char*)smem[cur] + jj*8192;
        const char* vbase = (const char*)smem[cur] + 16384 + jj*8192;

        f32x16 s0, s1;
#pragma unroll
        for (int i = 0; i < 16; ++i) { s0[i] = 0.f; s1[i] = 0.f; }

        __builtin_amdgcn_s_setprio(1);
#pragma unroll
        for (int st = 0; st < 4; ++st) {
          bf16x8 k0 = *(const bf16x8*)(kbase + roff[0][st]);
          bf16x8 k1 = *(const bf16x8*)(kbase + roff[1][st]);
          s0 = __builtin_amdgcn_mfma_f32_32x32x16_bf16(k0, qf[st], s0, 0, 0, 0);
          s1 = __builtin_amdgcn_mfma_f32_32x32x16_bf16(k1, qf[st], s1, 0, 0, 0);
        }
        __builtin_amdgcn_s_setprio(0);

        if (kv0 + 63 > qg - 31) {
#pragma unroll
          for (int r = 0; r < 16; ++r) {
            int kl = (r&3) + 8*(r>>2) + 4*hl;
            if (kv0 + kl      > qg) s0[r] = -1e30f;
            if (kv0 + 32 + kl > qg) s1[r] = -1e30f;
          }
        }

#pragma unroll
        for (int j = 0; j < 2; ++j) {
          const f32x16& sj = j ? s1 : s0;
          float p[16];
#pragma unroll
          for (int r = 0; r < 16; ++r) p[r] = __builtin_amdgcn_exp2f(sj[r]);
          float t0 = (p[0]+p[1]) + (p[2]+p[3]);
          float t1 = (p[4]+p[5]) + (p[6]+p[7]);
          float t2 = (p[8]+p[9]) + (p[10]+p[11]);
          float t3 = (p[12]+p[13]) + (p[14]+p[15]);
          l += (t0+t1) + (t2+t3);
          uint32_t a0,a1,a2,a3,b0,b1,b2,b3;
          CVTPK(a0, p[0],  p[1]);  CVTPK(a1, p[2],  p[3]);
          CVTPK(b0, p[4],  p[5]);  CVTPK(b1, p[6],  p[7]);
          CVTPK(a2, p[8],  p[9]);  CVTPK(a3, p[10], p[11]);
          CVTPK(b2, p[12], p[13]); CVTPK(b3, p[14], p[15]);
          SWAP32(a0, b0); SWAP32(a1, b1); SWAP32(a2, b2); SWAP32(a3, b3);
          union { uint32_t u[4]; bf16x8 v; } pf0, pf1;
          pf0.u[0]=a0; pf0.u[1]=a1; pf0.u[2]=b0; pf0.u[3]=b1;   // k-slot 2j
          pf1.u[0]=a2; pf1.u[1]=a3; pf1.u[2]=b2; pf1.u[3]=b3;   // k-slot 2j+1
          bf16x8 v00 = *(const bf16x8*)(vbase + roff[0][2*j]);
          bf16x8 v01 = *(const bf16x8*)(vbase + roff[1][2*j]);
          bf16x8 v10 = *(const bf16x8*)(vbase + roff[0][2*j + 1]);
          bf16x8 v11 = *(const bf16x8*)(vbase + roff[1][2*j + 1]);
          __builtin_amdgcn_s_setprio(1);
          o0a = __builtin_amdgcn_mfma_f32_32x32x16_bf16(v00, pf0.v, o0a, 0, 0, 0);
          o1a = __builtin_amdgcn_mfma_f32_32x32x16_bf16(v01, pf0.v, o1a, 0, 0, 0);
          o0b = __builtin_amdgcn_mfma_f32_32x32x16_bf16(v10, pf1.v, o0b, 0, 0, 0);
          o1b = __builtin_amdgcn_mfma_f32_32x32x16_bf16(v11, pf1.v, o1b, 0, 0, 0);
          __builtin_amdgcn_s_setprio(0);
        }
      }
    }
    __syncthreads();
  }
#undef STAGE

  // epilogue: combine split accumulators + half-wave sums, normalize, pack.
  f32x16 o0 = o0a + o0b;
  f32x16 o1 = o1a + o1b;
  l += __shfl_xor(l, 32);
  float inv = 1.f / l;
  o0 *= inv; o1 *= inv;

  // obuf[128 q][64 d] bf16 (16KB), 8B-granule XOR swizzle.
  unsigned short* obuf = (unsigned short*)smem;
  int qrow = wid*32 + l31;
  int xk = (qrow & 7) << 1;
#pragma unroll
  for (int g = 0; g < 4; ++g) {
    uint32_t w0, w1;
    CVTPK(w0, o0[4*g],   o0[4*g+1]);
    CVTPK(w1, o0[4*g+2], o0[4*g+3]);
    uint2 pk0 = {w0, w1};
    *(uint2*)&obuf[qrow*64 + (((2*g + hl) ^ xk) << 2)] = pk0;
    CVTPK(w0, o1[4*g],   o1[4*g+1]);
    CVTPK(w1, o1[4*g+2], o1[4*g+3]);
    uint2 pk1 = {w0, w1};
    *(uint2*)&obuf[qrow*64 + (((8 + 2*g + hl) ^ xk) << 2)] = pk1;
  }
  __syncthreads();

#pragma unroll
  for (int it = 0; it < 4; ++it) {
    int idx2 = it*256 + tid;          // 0..1023
    int s = idx2 & 7, row = idx2 >> 3;
    int4 v4 = *(const int4*)&obuf[row*64 + ((s ^ (row & 7)) << 3)];
    int tq = qt*128 + row;
    *(int4*)(out + ((size_t)(b*SEQ) + tq)*D_MODEL + h*DHEAD + s*8) = v4;
  }
}

// ---------------- launcher ----------------
extern "C" void kernel_launch(void* const* d_in, const int* in_sizes, int n_in,
                              void* d_out, int out_size, void* d_ws, size_t ws_size,
                              hipStream_t stream) {
  const float* x      = (const float*)d_in[0];
  const float* qkv_w  = (const float*)d_in[2];
  const float* qkv_b  = (const float*)d_in[3];
  const float* proj_w = (const float*)d_in[4];
  const float* proj_b = (const float*)d_in[5];

  const size_t MB = 1024*1024;
  if (ws_size < 48*MB) return;
  char* w = (char*)d_ws;
  unsigned short* xb      = (unsigned short*)(w);
  unsigned short* wqkv_t  = (unsigned short*)(w + 8*MB);
  unsigned short* wproj_t = (unsigned short*)(w + 14*MB);
  unsigned short* qbuf    = (unsigned short*)(w + 16*MB);
  unsigned short* kbuf    = (unsigned short*)(w + 24*MB);
  unsigned short* vtbuf   = (unsigned short*)(w + 32*MB);
  unsigned short* aout    = (unsigned short*)(w + 40*MB);

  prep<<<6144, 256, 0, stream>>>(x, xb, qkv_w, wqkv_t, proj_w, wproj_t);
  gemm_bt<<<dim3(N3/BN, MROWS/BM), 256, 0, stream>>>(xb, wqkv_t, qkv_b, D_MODEL, N3,
                                                     qbuf, kbuf, vtbuf);
  attn_fwd<<<dim3(32*NQT128), 256, 0, stream>>>(qbuf, kbuf, vtbuf, aout);
  gemm_proj<<<dim3(D_MODEL/PN, MROWS/PM), 256, 0, stream>>>(aout, wproj_t, proj_b, (float*)d_out);
}